// Round 1
// baseline (1600.039 us; speedup 1.0000x reference)
//
#include <hip/hip_runtime.h>
#include <hip/hip_bf16.h>

// OrbitalGenerator: 1024 independent [128x256] slices through a 4-layer MPNN.
// One block per orbital o; per-o intermediates live in 128KB of LDS (bf16);
// feats residual lives in d_out (fp32). All matmuls via mfma_f32_16x16x32_bf16.

#define O_TOT 1024
#define NNUC 128
#define FDIM 256
#define NLAYERS 4

typedef __bf16 bf16x8 __attribute__((ext_vector_type(8)));
typedef float f32x4 __attribute__((ext_vector_type(4)));

static __device__ __forceinline__ unsigned short f2bf(float f) {
  __bf16 b = (__bf16)f;
  unsigned short u;
  __builtin_memcpy(&u, &b, 2);
  return u;
}
static __device__ __forceinline__ float bf2f(unsigned short u) {
  unsigned int x = ((unsigned int)u) << 16;
  float f;
  __builtin_memcpy(&f, &x, 4);
  return f;
}

struct alignas(8) US4 { unsigned short a, b, c, d; };

// Swizzles: spread 16 rows (512B / 256B apart) across 8 distinct 16B bank slots.
static __device__ __forceinline__ int swzA(int row, int cb) {  // [128][512B] geometry
  return row * 512 + (cb ^ ((row & 7) << 4));
}
static __device__ __forceinline__ int swzV(int row, int cb) {  // [256][256B] geometry
  return row * 256 + (cb ^ ((row & 7) << 4));
}

// ---------------- setup kernels ----------------

// orbital -> (nucleus, orbital-type) map, including the spin permutation.
__global__ void k_orbmap(const int* __restrict__ charges, const int* __restrict__ n_up_p,
                         const int* __restrict__ n_down_p, int* __restrict__ orb_nuc,
                         int* __restrict__ orb_t) {
  __shared__ int off[129];
  __shared__ int prec[128];
  int tid = threadIdx.x;
  if (tid == 0) {
    int a = 0;
    for (int n = 0; n < 128; ++n) { off[n] = a; a += charges[n]; }
    off[128] = a;
  }
  if (tid < 128) prec[tid] = charges[tid] * (charges[tid] - 1) / 2;
  __syncthreads();
  int nu = *n_up_p, nd = *n_down_p;
  for (int o = tid; o < O_TOT; o += 256) {
    int e;
    if (o < nu) e = o;
    else if (o < 512) e = o + nd;
    else if (o < 512 + nd) e = o + nu - 512;
    else e = o;
    int nn = -1, tt = 0;
    for (int n = 0; n < 128; ++n) {
      if (e >= off[n] && e < off[n + 1]) { nn = n; tt = prec[n] + (e - off[n]); }
    }
    orb_nuc[o] = nn;
    orb_t[o] = tt;
  }
}

// edge featurization + per-layer/head edge weights: ewb[l][h][i][j] bf16
__global__ void k_ew(const float* __restrict__ coords, const float* __restrict__ W_edge,
                     unsigned short* __restrict__ ewb) {
  int i = blockIdx.x, j = threadIdx.x;
  float dx = coords[i * 3 + 0] - coords[j * 3 + 0];
  float dy = coords[i * 3 + 1] - coords[j * 3 + 1];
  float dz = coords[i * 3 + 2] - coords[j * 3 + 2];
  float norm = sqrtf(dx * dx + dy * dy + dz * dz + 1e-12f);
  float inv = 1.f / (1.f + norm);
  float e[7];
  e[0] = dx * inv; e[1] = dy * inv; e[2] = dz * inv;
  e[3] = log1pf(norm);
  e[4] = 1.f / (1.f + expf(-(norm - 2.f)));
  e[5] = 1.f / (1.f + expf(-(norm - 4.f)));
  e[6] = 1.f / (1.f + expf(-(norm - 6.f)));
  for (int l = 0; l < 4; ++l)
    for (int h = 0; h < 8; ++h) {
      float s = 0.f;
      for (int k = 0; k < 7; ++k) s += e[k] * W_edge[(l * 7 + k) * 8 + h];
      ewb[((l * 8 + h) * 128 + i) * 128 + j] = f2bf(s);
    }
}

// transpose W_val / W_out to bf16 [l][g][f] so MFMA B-fragments read contiguously
__global__ void k_wt(const float* __restrict__ Wv, const float* __restrict__ Wo,
                     unsigned short* __restrict__ WvT, unsigned short* __restrict__ WoT) {
  int idx = blockIdx.x * 256 + threadIdx.x;  // 4*256*256
  int l = idx >> 16, r = idx & 65535, g = r >> 8, f = r & 255;
  int src = (l << 16) + f * 256 + g;
  WvT[idx] = f2bf(Wv[src]);
  WoT[idx] = f2bf(Wo[src]);
}

// nucb[l][i][g] = nuc_feats[i,:] @ W_nuc[l][:,g]  (fp32)
__global__ void k_nucb(const float* __restrict__ nuc_feats, const float* __restrict__ W_nuc,
                       float* __restrict__ nucb) {
  int b = blockIdx.x;  // l*128 + i
  int l = b >> 7, i = b & 127;
  int g = threadIdx.x;
  __shared__ float row[256];
  row[g] = nuc_feats[i * 256 + g];
  __syncthreads();
  const float* Wn = W_nuc + l * 65536;
  float s = 0.f;
  for (int f = 0; f < 256; ++f) s += row[f] * Wn[f * 256 + g];
  nucb[b * 256 + g] = s;
}

// ---------------- fused main kernel: one block per orbital ----------------

__global__ __launch_bounds__(512, 1) void k_main(
    float* __restrict__ feats,               // d_out [1024][128][256] fp32
    const float* __restrict__ W_orb,         // [136][256]
    const unsigned short* __restrict__ WvT,  // [4][256][256] bf16 (g-major)
    const unsigned short* __restrict__ WoT,  // [4][256][256] bf16 (g-major)
    const unsigned short* __restrict__ ewb,  // [4][8][128][128] bf16
    const float* __restrict__ nucb,          // [4][128][256] fp32
    const int* __restrict__ orb_nuc, const int* __restrict__ orb_t) {
  __shared__ unsigned short S1[128 * 256];  // 64KB: h / msg
  __shared__ unsigned short S2[128 * 256];  // 64KB: valsT / t
  __shared__ float mean128[128];
  __shared__ float red[8];

  const int o = blockIdx.x;
  const int tid = threadIdx.x;
  const int wave = tid >> 6;
  const int lane = tid & 63;
  const int l16 = lane & 15;           // tile row (A) / tile col (B, D)
  const int kgrp = (lane >> 4) << 3;   // k element group offset: 0,8,16,24
  const int rgrp = (lane >> 4) << 2;   // D row group: 0,4,8,12

  float* fo = feats + (size_t)o * 32768;
  const int nn = orb_nuc[o];
  const int tt = orb_t[o];

  char* s1 = (char*)S1;
  char* s2 = (char*)S2;

  for (int l = 0; l < NLAYERS; ++l) {
    // ---- LN1: center feats rows, write bf16 to S1; rstd folded into GEMM1 ----
    float maxvar = 0.f;
    if (l == 0) {
      // initial feats: zero except row nn = W_orb[tt] -- synthesized, never materialized
      US4 z{0, 0, 0, 0};
      for (int r = 0; r < 16; ++r) {
        int n = wave * 16 + r;
        *(US4*)(s1 + swzA(n, lane * 8)) = z;
      }
      if (nn >= 0 && (nn >> 4) == wave) {
        const float4 v = *(const float4*)(W_orb + tt * 256 + lane * 4);
        float s = v.x + v.y + v.z + v.w;
        float ss = v.x * v.x + v.y * v.y + v.z * v.z + v.w * v.w;
        for (int of = 32; of; of >>= 1) { s += __shfl_xor(s, of); ss += __shfl_xor(ss, of); }
        float mean = s * (1.f / 256.f);
        float var = ss * (1.f / 256.f) - mean * mean;
        maxvar = var;
        US4 c4{f2bf(v.x - mean), f2bf(v.y - mean), f2bf(v.z - mean), f2bf(v.w - mean)};
        *(US4*)(s1 + swzA(nn, lane * 8)) = c4;
      }
    } else {
      for (int r = 0; r < 16; ++r) {
        int n = wave * 16 + r;
        const float4 v = *(const float4*)(fo + n * 256 + lane * 4);
        float s = v.x + v.y + v.z + v.w;
        float ss = v.x * v.x + v.y * v.y + v.z * v.z + v.w * v.w;
        for (int of = 32; of; of >>= 1) { s += __shfl_xor(s, of); ss += __shfl_xor(ss, of); }
        float mean = s * (1.f / 256.f);
        float var = ss * (1.f / 256.f) - mean * mean;
        maxvar = fmaxf(maxvar, var);
        US4 c4{f2bf(v.x - mean), f2bf(v.y - mean), f2bf(v.z - mean), f2bf(v.w - mean)};
        *(US4*)(s1 + swzA(n, lane * 8)) = c4;
      }
    }
    if (lane == 0) red[wave] = maxvar;
    __syncthreads();  // B1
    float mv = red[0];
    for (int w = 1; w < 8; ++w) mv = fmaxf(mv, red[w]);
    const float rstd = rsqrtf(mv + 1.f);

    // ---- GEMM1: valsT[g][n] = rstd * (h @ W_val)   (S1 -> S2) ----
    {
      const unsigned short* Wl = WvT + l * 65536;
      const int m0 = (wave & 3) * 32, m1 = m0 + 16;
      const int ntb = (wave >> 2) * 8;
      for (int nti = 0; nti < 8; ++nti) {
        const int g0 = (ntb + nti) * 16;
        const unsigned short* brow = Wl + (g0 + l16) * 256 + kgrp;
        bf16x8 b[8];
#pragma unroll
        for (int k0 = 0; k0 < 8; ++k0) b[k0] = *(const bf16x8*)(brow + k0 * 32);
        f32x4 acc0 = {0.f, 0.f, 0.f, 0.f}, acc1 = {0.f, 0.f, 0.f, 0.f};
#pragma unroll
        for (int k0 = 0; k0 < 8; ++k0) {
          bf16x8 a0 = *(const bf16x8*)(s1 + swzA(m0 + l16, (k0 * 32 + kgrp) * 2));
          bf16x8 a1 = *(const bf16x8*)(s1 + swzA(m1 + l16, (k0 * 32 + kgrp) * 2));
          acc0 = __builtin_amdgcn_mfma_f32_16x16x32_bf16(a0, b[k0], acc0, 0, 0, 0);
          acc1 = __builtin_amdgcn_mfma_f32_16x16x32_bf16(a1, b[k0], acc1, 0, 0, 0);
        }
        const int gg = g0 + l16;
        US4 o0{f2bf(acc0[0] * rstd), f2bf(acc0[1] * rstd), f2bf(acc0[2] * rstd), f2bf(acc0[3] * rstd)};
        US4 o1{f2bf(acc1[0] * rstd), f2bf(acc1[1] * rstd), f2bf(acc1[2] * rstd), f2bf(acc1[3] * rstd)};
        *(US4*)(s2 + swzV(gg, (m0 + rgrp) * 2)) = o0;
        *(US4*)(s2 + swzV(gg, (m1 + rgrp) * 2)) = o1;
      }
    }
    __syncthreads();  // B2

    // ---- MSG: S1[i][f] = sum_j ew[h][i][j] * valsT[f][j] + nucb[i][f] ----
    {
      const int hh = wave;
      const unsigned short* ewh = ewb + (l * 8 + hh) * 16384;
      const float* nbl = nucb + l * 32768;
      for (int mt = 0; mt < 8; ++mt) {
        const int i0 = mt * 16;
        bf16x8 a[4];
#pragma unroll
        for (int k0 = 0; k0 < 4; ++k0)
          a[k0] = *(const bf16x8*)(ewh + (i0 + l16) * 128 + k0 * 32 + kgrp);
#pragma unroll
        for (int nt = 0; nt < 2; ++nt) {
          const int d0 = nt * 16;
          f32x4 acc = {0.f, 0.f, 0.f, 0.f};
#pragma unroll
          for (int k0 = 0; k0 < 4; ++k0) {
            bf16x8 b = *(const bf16x8*)(s2 + swzV(hh * 32 + d0 + l16, (k0 * 32 + kgrp) * 2));
            acc = __builtin_amdgcn_mfma_f32_16x16x32_bf16(a[k0], b, acc, 0, 0, 0);
          }
          const int f = hh * 32 + d0 + l16;
#pragma unroll
          for (int r = 0; r < 4; ++r) {
            const int i = i0 + rgrp + r;
            float v = acc[r] + nbl[i * 256 + f];
            *(unsigned short*)(s1 + swzA(i, f * 2)) = f2bf(v);
          }
        }
      }
    }
    __syncthreads();  // B3

    // ---- LN2 pass A: mean/var per row of msg (S1), max-var -> rstd2 ----
    {
      float mv2 = 0.f;
      for (int r = 0; r < 16; ++r) {
        const int n = wave * 16 + r;
        US4 x4 = *(const US4*)(s1 + swzA(n, lane * 8));
        float x0 = bf2f(x4.a), x1 = bf2f(x4.b), x2 = bf2f(x4.c), x3 = bf2f(x4.d);
        float s = x0 + x1 + x2 + x3;
        float ss = x0 * x0 + x1 * x1 + x2 * x2 + x3 * x3;
        for (int of = 32; of; of >>= 1) { s += __shfl_xor(s, of); ss += __shfl_xor(ss, of); }
        float mean = s * (1.f / 256.f);
        float var = ss * (1.f / 256.f) - mean * mean;
        mv2 = fmaxf(mv2, var);
        if (lane == 0) mean128[n] = mean;
      }
      if (lane == 0) red[wave] = mv2;
    }
    __syncthreads();  // B4
    {
      float mv2 = red[0];
      for (int w = 1; w < 8; ++w) mv2 = fmaxf(mv2, red[w]);
      const float rstd2 = rsqrtf(mv2 + 1.f);
      // pass B: t = tanh((msg - mean) * rstd2) -> S2 (row-major geometry)
      for (int r = 0; r < 16; ++r) {
        const int n = wave * 16 + r;
        US4 x4 = *(const US4*)(s1 + swzA(n, lane * 8));
        const float mn = mean128[n];
        US4 t4{f2bf(tanhf((bf2f(x4.a) - mn) * rstd2)),
               f2bf(tanhf((bf2f(x4.b) - mn) * rstd2)),
               f2bf(tanhf((bf2f(x4.c) - mn) * rstd2)),
               f2bf(tanhf((bf2f(x4.d) - mn) * rstd2))};
        *(US4*)(s2 + swzA(n, lane * 8)) = t4;
      }
    }
    __syncthreads();  // B4b

    // ---- GEMM2: feats += t @ W_out  (S2 -> global, l=0 writes init+delta) ----
    {
      const unsigned short* Wl = WoT + l * 65536;
      const int m0 = (wave & 3) * 32, m1 = m0 + 16;
      const int ntb = (wave >> 2) * 8;
      for (int nti = 0; nti < 8; ++nti) {
        const int g0 = (ntb + nti) * 16;
        const unsigned short* brow = Wl + (g0 + l16) * 256 + kgrp;
        bf16x8 b[8];
#pragma unroll
        for (int k0 = 0; k0 < 8; ++k0) b[k0] = *(const bf16x8*)(brow + k0 * 32);
        f32x4 acc0 = {0.f, 0.f, 0.f, 0.f}, acc1 = {0.f, 0.f, 0.f, 0.f};
#pragma unroll
        for (int k0 = 0; k0 < 8; ++k0) {
          bf16x8 a0 = *(const bf16x8*)(s2 + swzA(m0 + l16, (k0 * 32 + kgrp) * 2));
          bf16x8 a1 = *(const bf16x8*)(s2 + swzA(m1 + l16, (k0 * 32 + kgrp) * 2));
          acc0 = __builtin_amdgcn_mfma_f32_16x16x32_bf16(a0, b[k0], acc0, 0, 0, 0);
          acc1 = __builtin_amdgcn_mfma_f32_16x16x32_bf16(a1, b[k0], acc1, 0, 0, 0);
        }
        const int gg = g0 + l16;
        if (l == 0) {
#pragma unroll
          for (int r = 0; r < 4; ++r) {
            int n = m0 + rgrp + r;
            float base = (n == nn) ? W_orb[tt * 256 + gg] : 0.f;
            fo[n * 256 + gg] = base + acc0[r];
          }
#pragma unroll
          for (int r = 0; r < 4; ++r) {
            int n = m1 + rgrp + r;
            float base = (n == nn) ? W_orb[tt * 256 + gg] : 0.f;
            fo[n * 256 + gg] = base + acc1[r];
          }
        } else {
#pragma unroll
          for (int r = 0; r < 4; ++r) fo[(m0 + rgrp + r) * 256 + gg] += acc0[r];
#pragma unroll
          for (int r = 0; r < 4; ++r) fo[(m1 + rgrp + r) * 256 + gg] += acc1[r];
        }
      }
    }
    __syncthreads();  // B5: drain global stores before next layer's LN1 reads
  }
}

// ---------------- launcher ----------------

extern "C" void kernel_launch(void* const* d_in, const int* in_sizes, int n_in,
                              void* d_out, int out_size, void* d_ws, size_t ws_size,
                              hipStream_t stream) {
  const float* coords = (const float*)d_in[0];
  const int* charges = (const int*)d_in[1];
  const int* n_up = (const int*)d_in[3];
  const int* n_down = (const int*)d_in[4];
  const float* nuc_feats = (const float*)d_in[5];
  const float* W_orb = (const float*)d_in[7];
  const float* W_edge = (const float*)d_in[8];
  const float* W_val = (const float*)d_in[9];
  const float* W_nuc = (const float*)d_in[10];
  const float* W_out = (const float*)d_in[11];
  float* out = (float*)d_out;

  char* ws = (char*)d_ws;
  int* orb_nuc = (int*)ws;                                        // 4KB
  int* orb_t = (int*)(ws + 4096);                                 // 4KB
  unsigned short* ewb = (unsigned short*)(ws + 8192);             // 1MB
  unsigned short* WvT = (unsigned short*)(ws + 8192 + 1048576);   // 512KB
  unsigned short* WoT = WvT + 262144;                             // 512KB
  float* nucb = (float*)(ws + 8192 + 1048576 + 1048576);          // 512KB

  k_orbmap<<<dim3(1), dim3(256), 0, stream>>>(charges, n_up, n_down, orb_nuc, orb_t);
  k_ew<<<dim3(128), dim3(128), 0, stream>>>(coords, W_edge, ewb);
  k_wt<<<dim3(1024), dim3(256), 0, stream>>>(W_val, W_out, WvT, WoT);
  k_nucb<<<dim3(512), dim3(256), 0, stream>>>(nuc_feats, W_nuc, nucb);
  k_main<<<dim3(O_TOT), dim3(512), 0, stream>>>(out, W_orb, WvT, WoT, ewb, nucb,
                                                orb_nuc, orb_t);
}

// Round 2
// 1190.444 us; speedup vs baseline: 1.3441x; 1.3441x over previous
//
#include <hip/hip_runtime.h>
#include <hip/hip_bf16.h>

// OrbitalGenerator: 1024 independent [128x256] slices through a 4-layer MPNN.
// One block per orbital. feats lives in REGISTERS (fr[2][8][4] per lane, laid
// out as GEMM2 D-fragments); h/vals/msg/t ping-pong through 128KB LDS (bf16).
// All matmuls via mfma_f32_16x16x32_bf16, fp32 accumulation.

#define O_TOT 1024

typedef __bf16 bf16x8 __attribute__((ext_vector_type(8)));
typedef float f32x4 __attribute__((ext_vector_type(4)));

static __device__ __forceinline__ unsigned short f2bf(float f) {
  __bf16 b = (__bf16)f;
  unsigned short u;
  __builtin_memcpy(&u, &b, 2);
  return u;
}
static __device__ __forceinline__ float bf2f(unsigned short u) {
  unsigned int x = ((unsigned int)u) << 16;
  float f;
  __builtin_memcpy(&f, &x, 4);
  return f;
}
static __device__ __forceinline__ float ftanh(float x) {
  // tanh(x) = 1 - 2/(exp(2x)+1); v_exp + v_rcp, saturates correctly at +-inf
  float e = __expf(2.f * x);
  return 1.f - 2.f * __builtin_amdgcn_rcpf(e + 1.f);
}

struct alignas(8) US4 { unsigned short a, b, c, d; };

// XOR swizzles with 2 row bits -> 16 distinct 16B slots per 16 consecutive rows.
static __device__ __forceinline__ int swzA(int row, int cb) {  // [128][512B]
  return row * 512 + (cb ^ ((row & 7) << 4) ^ (((row >> 3) & 1) << 5));
}
static __device__ __forceinline__ int swzV(int row, int cb) {  // [256][256B]
  return row * 256 + (cb ^ ((row & 7) << 4) ^ (((row >> 3) & 1) << 5));
}

// ---------------- setup kernels ----------------

__global__ void k_orbmap(const int* __restrict__ charges, const int* __restrict__ n_up_p,
                         const int* __restrict__ n_down_p, int* __restrict__ orb_nuc,
                         int* __restrict__ orb_t) {
  __shared__ int off[129];
  __shared__ int prec[128];
  int tid = threadIdx.x;
  if (tid == 0) {
    int a = 0;
    for (int n = 0; n < 128; ++n) { off[n] = a; a += charges[n]; }
    off[128] = a;
  }
  if (tid < 128) prec[tid] = charges[tid] * (charges[tid] - 1) / 2;
  __syncthreads();
  int nu = *n_up_p, nd = *n_down_p;
  for (int o = tid; o < O_TOT; o += 256) {
    int e;
    if (o < nu) e = o;
    else if (o < 512) e = o + nd;
    else if (o < 512 + nd) e = o + nu - 512;
    else e = o;
    int nn = -1, tt = 0;
    for (int n = 0; n < 128; ++n) {
      if (e >= off[n] && e < off[n + 1]) { nn = n; tt = prec[n] + (e - off[n]); }
    }
    orb_nuc[o] = nn;
    orb_t[o] = tt;
  }
}

__global__ void k_ew(const float* __restrict__ coords, const float* __restrict__ W_edge,
                     unsigned short* __restrict__ ewb) {
  int i = blockIdx.x, j = threadIdx.x;
  float dx = coords[i * 3 + 0] - coords[j * 3 + 0];
  float dy = coords[i * 3 + 1] - coords[j * 3 + 1];
  float dz = coords[i * 3 + 2] - coords[j * 3 + 2];
  float norm = sqrtf(dx * dx + dy * dy + dz * dz + 1e-12f);
  float inv = 1.f / (1.f + norm);
  float e[7];
  e[0] = dx * inv; e[1] = dy * inv; e[2] = dz * inv;
  e[3] = log1pf(norm);
  e[4] = 1.f / (1.f + expf(-(norm - 2.f)));
  e[5] = 1.f / (1.f + expf(-(norm - 4.f)));
  e[6] = 1.f / (1.f + expf(-(norm - 6.f)));
  for (int l = 0; l < 4; ++l)
    for (int h = 0; h < 8; ++h) {
      float s = 0.f;
      for (int k = 0; k < 7; ++k) s += e[k] * W_edge[(l * 7 + k) * 8 + h];
      ewb[((l * 8 + h) * 128 + i) * 128 + j] = f2bf(s);
    }
}

__global__ void k_wt(const float* __restrict__ Wv, const float* __restrict__ Wo,
                     unsigned short* __restrict__ WvT, unsigned short* __restrict__ WoT) {
  int idx = blockIdx.x * 256 + threadIdx.x;  // 4*256*256
  int l = idx >> 16, r = idx & 65535, g = r >> 8, f = r & 255;
  int src = (l << 16) + f * 256 + g;
  WvT[idx] = f2bf(Wv[src]);
  WoT[idx] = f2bf(Wo[src]);
}

// nucbT[l][g][i] = nuc_feats[i,:] @ W_nuc[l][:,g]  (fp32, TRANSPOSED for float4 adds)
__global__ void k_nucbT(const float* __restrict__ nuc_feats, const float* __restrict__ W_nuc,
                        float* __restrict__ nucbT) {
  int b = blockIdx.x;  // l*128 + i
  int l = b >> 7, i = b & 127;
  int g = threadIdx.x;
  __shared__ float row[256];
  row[g] = nuc_feats[i * 256 + g];
  __syncthreads();
  const float* Wn = W_nuc + l * 65536;
  float s = 0.f;
  for (int f = 0; f < 256; ++f) s += row[f] * Wn[f * 256 + g];
  nucbT[(l * 256 + g) * 128 + i] = s;
}

// ---------------- fused main kernel ----------------

__global__ __launch_bounds__(512, 2) void k_main(
    float* __restrict__ feats,               // d_out [1024][128][256] fp32
    const float* __restrict__ W_orb,         // [136][256]
    const unsigned short* __restrict__ WvT,  // [4][256][256] bf16 (g-major)
    const unsigned short* __restrict__ WoT,  // [4][256][256] bf16 (g-major)
    const unsigned short* __restrict__ ewb,  // [4][8][128][128] bf16
    const float* __restrict__ nucbT,         // [4][256][128] fp32
    const int* __restrict__ orb_nuc, const int* __restrict__ orb_t) {
  __shared__ char SBUF[131072];     // s1: h/msg [128][512B]; s2: valsT [256][256B] then t
  __shared__ float lnA[2][128][2];  // LN1 cross-wave partials [g-half][row][s,ss]
  __shared__ float ln2[8][128][2];  // LN2 per-head partials   [head][row][s,ss]
  __shared__ float red[8];

  char* s1 = SBUF;
  char* s2 = SBUF + 65536;

  const int o = blockIdx.x;
  const int tid = threadIdx.x;
  const int wave = tid >> 6;
  const int lane = tid & 63;
  const int l16 = lane & 15;
  const int kgrp = (lane >> 4) << 3;  // A/B fragment k-offset: 0,8,16,24
  const int rgrp = (lane >> 4) << 2;  // D fragment row group: 0,4,8,12
  const int mh = wave & 3, gh = wave >> 2;
  const int m0 = mh * 32;    // this wave's 32 output rows
  const int G0 = gh * 128;   // this wave's g-half

  const int nn = orb_nuc[o];
  const int tt = orb_t[o];
  float* fo = feats + (size_t)o * 32768;

  // feats in registers: fr[mt][nti][r] = feats[m0+mt*16+rgrp+r][G0+nti*16+l16]
  float fr[2][8][4];
#pragma unroll
  for (int mt = 0; mt < 2; ++mt)
#pragma unroll
    for (int r = 0; r < 4; ++r) {
      const int n = m0 + mt * 16 + rgrp + r;
#pragma unroll
      for (int nti = 0; nti < 8; ++nti)
        fr[mt][nti][r] = (n == nn) ? W_orb[tt * 256 + G0 + nti * 16 + l16] : 0.f;
    }

  for (int l = 0; l < 4; ++l) {
    // ---- LN1 stage 1: per-row partial (s,ss) over this wave's g-half ----
    {
      float sp[2][4], qp[2][4];
#pragma unroll
      for (int mt = 0; mt < 2; ++mt)
#pragma unroll
        for (int r = 0; r < 4; ++r) {
          float s = 0.f, q = 0.f;
#pragma unroll
          for (int nti = 0; nti < 8; ++nti) {
            float v = fr[mt][nti][r];
            s += v; q += v * v;
          }
          sp[mt][r] = s; qp[mt][r] = q;
        }
#pragma unroll
      for (int of = 1; of < 16; of <<= 1)
#pragma unroll
        for (int mt = 0; mt < 2; ++mt)
#pragma unroll
          for (int r = 0; r < 4; ++r) {
            sp[mt][r] += __shfl_xor(sp[mt][r], of);
            qp[mt][r] += __shfl_xor(qp[mt][r], of);
          }
      if (l16 == 0) {
#pragma unroll
        for (int mt = 0; mt < 2; ++mt)
#pragma unroll
          for (int r = 0; r < 4; ++r) {
            const int n = m0 + mt * 16 + rgrp + r;
            lnA[gh][n][0] = sp[mt][r];
            lnA[gh][n][1] = qp[mt][r];
          }
      }
    }
    __syncthreads();  // B1: lnA ready; also orders prior S1 reads vs h writes

    // ---- LN1 stage 2: center (register source), write h bf16 to S1 ----
    {
      float maxvar = 0.f;
#pragma unroll
      for (int mt = 0; mt < 2; ++mt)
#pragma unroll
        for (int r = 0; r < 4; ++r) {
          const int n = m0 + mt * 16 + rgrp + r;
          const float S = lnA[0][n][0] + lnA[1][n][0];
          const float Q = lnA[0][n][1] + lnA[1][n][1];
          const float mean = S * (1.f / 256.f);
          const float var = Q * (1.f / 256.f) - mean * mean;
          maxvar = fmaxf(maxvar, var);
#pragma unroll
          for (int nti = 0; nti < 8; ++nti)
            *(unsigned short*)(s1 + swzA(n, (G0 + nti * 16 + l16) * 2)) =
                f2bf(fr[mt][nti][r] - mean);
        }
      maxvar = fmaxf(maxvar, __shfl_xor(maxvar, 16));
      maxvar = fmaxf(maxvar, __shfl_xor(maxvar, 32));
      if (lane == 0) red[wave] = maxvar;
    }
    __syncthreads();  // B2: S1(h) + red ready

    // ---- GEMM1: valsT[g][n] = rstd * (h @ W_val), S1 -> S2 ----
    {
      float mv = red[0];
#pragma unroll
      for (int w = 1; w < 8; ++w) mv = fmaxf(mv, red[w]);
      const float rstd = rsqrtf(mv + 1.f);
      const unsigned short* Wl = WvT + l * 65536;
      bf16x8 A0[8], A1[8];  // hoisted A-fragments (both m-tiles, full K)
#pragma unroll
      for (int k0 = 0; k0 < 8; ++k0) {
        A0[k0] = *(const bf16x8*)(s1 + swzA(m0 + l16, (k0 * 32 + kgrp) * 2));
        A1[k0] = *(const bf16x8*)(s1 + swzA(m0 + 16 + l16, (k0 * 32 + kgrp) * 2));
      }
#pragma unroll
      for (int nti = 0; nti < 8; ++nti) {
        const int gg = G0 + nti * 16 + l16;
        const unsigned short* brow = Wl + gg * 256 + kgrp;
        bf16x8 b[8];
#pragma unroll
        for (int k0 = 0; k0 < 8; ++k0) b[k0] = *(const bf16x8*)(brow + k0 * 32);
        f32x4 acc0 = {0.f, 0.f, 0.f, 0.f}, acc1 = {0.f, 0.f, 0.f, 0.f};
#pragma unroll
        for (int k0 = 0; k0 < 8; ++k0) {
          acc0 = __builtin_amdgcn_mfma_f32_16x16x32_bf16(A0[k0], b[k0], acc0, 0, 0, 0);
          acc1 = __builtin_amdgcn_mfma_f32_16x16x32_bf16(A1[k0], b[k0], acc1, 0, 0, 0);
        }
        US4 o0{f2bf(acc0[0] * rstd), f2bf(acc0[1] * rstd), f2bf(acc0[2] * rstd), f2bf(acc0[3] * rstd)};
        US4 o1{f2bf(acc1[0] * rstd), f2bf(acc1[1] * rstd), f2bf(acc1[2] * rstd), f2bf(acc1[3] * rstd)};
        *(US4*)(s2 + swzV(gg, (m0 + rgrp) * 2)) = o0;
        *(US4*)(s2 + swzV(gg, (m0 + 16 + rgrp) * 2)) = o1;
      }
    }
    __syncthreads();  // B3: S2(valsT) ready

    // ---- MSG: msg[i][f] = sum_j ew[h][i][j]*valsT[f][j] + nucbT[f][i] ----
    //      + in-epilogue LN2 partial stats (per-head) -> ln2
    {
      const unsigned short* ewh = ewb + (l * 8 + wave) * 16384;
      const float* nbT = nucbT + l * 32768;
      const int f0 = wave * 32 + l16;
      const int f1 = f0 + 16;
      bf16x8 B0[4], B1[4];  // hoisted: this head's valsT rows, full K=128
#pragma unroll
      for (int k0 = 0; k0 < 4; ++k0) {
        B0[k0] = *(const bf16x8*)(s2 + swzV(wave * 32 + l16, (k0 * 32 + kgrp) * 2));
        B1[k0] = *(const bf16x8*)(s2 + swzV(wave * 32 + 16 + l16, (k0 * 32 + kgrp) * 2));
      }
#pragma unroll
      for (int mt = 0; mt < 8; ++mt) {
        const int i0 = mt * 16;
        bf16x8 a[4];
#pragma unroll
        for (int k0 = 0; k0 < 4; ++k0)
          a[k0] = *(const bf16x8*)(ewh + (i0 + l16) * 128 + k0 * 32 + kgrp);
        f32x4 acc0 = {0.f, 0.f, 0.f, 0.f}, acc1 = {0.f, 0.f, 0.f, 0.f};
#pragma unroll
        for (int k0 = 0; k0 < 4; ++k0) {
          acc0 = __builtin_amdgcn_mfma_f32_16x16x32_bf16(a[k0], B0[k0], acc0, 0, 0, 0);
          acc1 = __builtin_amdgcn_mfma_f32_16x16x32_bf16(a[k0], B1[k0], acc1, 0, 0, 0);
        }
        const f32x4 nb0 = *(const f32x4*)(nbT + f0 * 128 + i0 + rgrp);
        const f32x4 nb1 = *(const f32x4*)(nbT + f1 * 128 + i0 + rgrp);
        float sp[4], qp[4];
#pragma unroll
        for (int r = 0; r < 4; ++r) {
          const float v0 = acc0[r] + nb0[r];
          const float v1 = acc1[r] + nb1[r];
          *(unsigned short*)(s1 + swzA(i0 + rgrp + r, f0 * 2)) = f2bf(v0);
          *(unsigned short*)(s1 + swzA(i0 + rgrp + r, f1 * 2)) = f2bf(v1);
          sp[r] = v0 + v1;
          qp[r] = v0 * v0 + v1 * v1;
        }
#pragma unroll
        for (int of = 1; of < 16; of <<= 1)
#pragma unroll
          for (int r = 0; r < 4; ++r) {
            sp[r] += __shfl_xor(sp[r], of);
            qp[r] += __shfl_xor(qp[r], of);
          }
        if (l16 == 0) {
#pragma unroll
          for (int r = 0; r < 4; ++r) {
            ln2[wave][i0 + rgrp + r][0] = sp[r];
            ln2[wave][i0 + rgrp + r][1] = qp[r];
          }
        }
      }
    }
    __syncthreads();  // B4: S1(msg) + ln2 ready

    // ---- LN2 combine (redundant per wave, no extra barrier) + pass B ----
    {
      float s0 = 0.f, q0 = 0.f, s1v = 0.f, q1v = 0.f;
#pragma unroll
      for (int h = 0; h < 8; ++h) {
        s0 += ln2[h][lane][0];        q0 += ln2[h][lane][1];
        s1v += ln2[h][lane + 64][0];  q1v += ln2[h][lane + 64][1];
      }
      const float mean_a = s0 * (1.f / 256.f);
      const float mean_b = s1v * (1.f / 256.f);
      float v0 = q0 * (1.f / 256.f) - mean_a * mean_a;
      float v1 = q1v * (1.f / 256.f) - mean_b * mean_b;
      float mv = fmaxf(v0, v1);
#pragma unroll
      for (int of = 1; of < 64; of <<= 1) mv = fmaxf(mv, __shfl_xor(mv, of));
      const float rstd2 = rsqrtf(mv + 1.f);
      const float meansel = (wave >= 4) ? mean_b : mean_a;
      // t = tanh((msg - mean) * rstd2): wave handles rows wave*16..+16
#pragma unroll
      for (int r = 0; r < 16; ++r) {
        const int n = wave * 16 + r;
        const float mn = __shfl(meansel, ((wave & 3) << 4) + r);
        US4 x4 = *(const US4*)(s1 + swzA(n, lane * 8));
        US4 t4{f2bf(ftanh((bf2f(x4.a) - mn) * rstd2)),
               f2bf(ftanh((bf2f(x4.b) - mn) * rstd2)),
               f2bf(ftanh((bf2f(x4.c) - mn) * rstd2)),
               f2bf(ftanh((bf2f(x4.d) - mn) * rstd2))};
        *(US4*)(s2 + swzA(n, lane * 8)) = t4;
      }
    }
    __syncthreads();  // B5: S2(t) ready

    // ---- GEMM2: fr += t @ W_out (registers; no global RMW) ----
    {
      const unsigned short* Wl = WoT + l * 65536;
      bf16x8 A0[8], A1[8];
#pragma unroll
      for (int k0 = 0; k0 < 8; ++k0) {
        A0[k0] = *(const bf16x8*)(s2 + swzA(m0 + l16, (k0 * 32 + kgrp) * 2));
        A1[k0] = *(const bf16x8*)(s2 + swzA(m0 + 16 + l16, (k0 * 32 + kgrp) * 2));
      }
#pragma unroll
      for (int nti = 0; nti < 8; ++nti) {
        const unsigned short* brow = Wl + (G0 + nti * 16 + l16) * 256 + kgrp;
        bf16x8 b[8];
#pragma unroll
        for (int k0 = 0; k0 < 8; ++k0) b[k0] = *(const bf16x8*)(brow + k0 * 32);
        f32x4 acc0 = {0.f, 0.f, 0.f, 0.f}, acc1 = {0.f, 0.f, 0.f, 0.f};
#pragma unroll
        for (int k0 = 0; k0 < 8; ++k0) {
          acc0 = __builtin_amdgcn_mfma_f32_16x16x32_bf16(A0[k0], b[k0], acc0, 0, 0, 0);
          acc1 = __builtin_amdgcn_mfma_f32_16x16x32_bf16(A1[k0], b[k0], acc1, 0, 0, 0);
        }
#pragma unroll
        for (int r = 0; r < 4; ++r) {
          fr[0][nti][r] += acc0[r];
          fr[1][nti][r] += acc1[r];
        }
      }
    }
    // no barrier needed: next phase touching LDS is LN1 stage2 (after next B1)
  }

  // ---- final store: stage fp32 through LDS for coalesced float4 stores ----
  __syncthreads();
  float* stage = (float*)SBUF;
#pragma unroll
  for (int mt = 0; mt < 2; ++mt)
#pragma unroll
    for (int r = 0; r < 4; ++r) {
      const int n = m0 + mt * 16 + rgrp + r;
#pragma unroll
      for (int nti = 0; nti < 8; ++nti)
        stage[n * 256 + G0 + nti * 16 + l16] = fr[mt][nti][r];
    }
  __syncthreads();
#pragma unroll
  for (int it = 0; it < 16; ++it) {
    const int idx = (it * 512 + tid) * 4;
    *(f32x4*)(fo + idx) = *(const f32x4*)(stage + idx);
  }
}

// ---------------- launcher ----------------

extern "C" void kernel_launch(void* const* d_in, const int* in_sizes, int n_in,
                              void* d_out, int out_size, void* d_ws, size_t ws_size,
                              hipStream_t stream) {
  const float* coords = (const float*)d_in[0];
  const int* charges = (const int*)d_in[1];
  const int* n_up = (const int*)d_in[3];
  const int* n_down = (const int*)d_in[4];
  const float* nuc_feats = (const float*)d_in[5];
  const float* W_orb = (const float*)d_in[7];
  const float* W_edge = (const float*)d_in[8];
  const float* W_val = (const float*)d_in[9];
  const float* W_nuc = (const float*)d_in[10];
  const float* W_out = (const float*)d_in[11];
  float* out = (float*)d_out;

  char* ws = (char*)d_ws;
  int* orb_nuc = (int*)ws;                                        // 4KB
  int* orb_t = (int*)(ws + 4096);                                 // 4KB
  unsigned short* ewb = (unsigned short*)(ws + 8192);             // 1MB
  unsigned short* WvT = (unsigned short*)(ws + 8192 + 1048576);   // 512KB
  unsigned short* WoT = WvT + 262144;                             // 512KB
  float* nucbT = (float*)(ws + 8192 + 1048576 + 1048576);         // 512KB

  k_orbmap<<<dim3(1), dim3(256), 0, stream>>>(charges, n_up, n_down, orb_nuc, orb_t);
  k_ew<<<dim3(128), dim3(128), 0, stream>>>(coords, W_edge, ewb);
  k_wt<<<dim3(1024), dim3(256), 0, stream>>>(W_val, W_out, WvT, WoT);
  k_nucbT<<<dim3(512), dim3(256), 0, stream>>>(nuc_feats, W_nuc, nucbT);
  k_main<<<dim3(O_TOT), dim3(512), 0, stream>>>(out, W_orb, WvT, WoT, ewb, nucbT,
                                                orb_nuc, orb_t);
}

// Round 3
// 1184.756 us; speedup vs baseline: 1.3505x; 1.0048x over previous
//
#include <hip/hip_runtime.h>
#include <hip/hip_bf16.h>

// OrbitalGenerator: 1024 independent [128x256] slices through a 4-layer MPNN.
// One block per orbital. feats lives in MFMA ACCUMULATORS (f32x4 fr[2][8],
// AGPR-resident: GEMM2 seeds its accumulator chains with fr, making the
// residual add free and keeping arch-VGPR pressure ~100 -> no scratch spill).
// h/vals/msg/t ping-pong through 128KB LDS (bf16), mfma_f32_16x16x32_bf16.

#define O_TOT 1024

typedef __bf16 bf16x8 __attribute__((ext_vector_type(8)));
typedef float f32x4 __attribute__((ext_vector_type(4)));

static __device__ __forceinline__ unsigned short f2bf(float f) {
  __bf16 b = (__bf16)f;
  unsigned short u;
  __builtin_memcpy(&u, &b, 2);
  return u;
}
static __device__ __forceinline__ float bf2f(unsigned short u) {
  unsigned int x = ((unsigned int)u) << 16;
  float f;
  __builtin_memcpy(&f, &x, 4);
  return f;
}
static __device__ __forceinline__ float ftanh(float x) {
  float e = __expf(2.f * x);
  return 1.f - 2.f * __builtin_amdgcn_rcpf(e + 1.f);
}

struct alignas(8) US4 { unsigned short a, b, c, d; };

// XOR swizzles with 2 row bits -> 16 distinct 16B slots per 16 consecutive rows.
static __device__ __forceinline__ int swzA(int row, int cb) {  // [128][512B]
  return row * 512 + (cb ^ ((row & 7) << 4) ^ (((row >> 3) & 1) << 5));
}
static __device__ __forceinline__ int swzV(int row, int cb) {  // [256][256B]
  return row * 256 + (cb ^ ((row & 7) << 4) ^ (((row >> 3) & 1) << 5));
}

// ---------------- setup kernels ----------------

__global__ void k_orbmap(const int* __restrict__ charges, const int* __restrict__ n_up_p,
                         const int* __restrict__ n_down_p, int* __restrict__ orb_nuc,
                         int* __restrict__ orb_t) {
  __shared__ int off[129];
  __shared__ int prec[128];
  int tid = threadIdx.x;
  if (tid == 0) {
    int a = 0;
    for (int n = 0; n < 128; ++n) { off[n] = a; a += charges[n]; }
    off[128] = a;
  }
  if (tid < 128) prec[tid] = charges[tid] * (charges[tid] - 1) / 2;
  __syncthreads();
  int nu = *n_up_p, nd = *n_down_p;
  for (int o = tid; o < O_TOT; o += 256) {
    int e;
    if (o < nu) e = o;
    else if (o < 512) e = o + nd;
    else if (o < 512 + nd) e = o + nu - 512;
    else e = o;
    int nn = -1, tt = 0;
    for (int n = 0; n < 128; ++n) {
      if (e >= off[n] && e < off[n + 1]) { nn = n; tt = prec[n] + (e - off[n]); }
    }
    orb_nuc[o] = nn;
    orb_t[o] = tt;
  }
}

__global__ void k_ew(const float* __restrict__ coords, const float* __restrict__ W_edge,
                     unsigned short* __restrict__ ewb) {
  int i = blockIdx.x, j = threadIdx.x;
  float dx = coords[i * 3 + 0] - coords[j * 3 + 0];
  float dy = coords[i * 3 + 1] - coords[j * 3 + 1];
  float dz = coords[i * 3 + 2] - coords[j * 3 + 2];
  float norm = sqrtf(dx * dx + dy * dy + dz * dz + 1e-12f);
  float inv = 1.f / (1.f + norm);
  float e[7];
  e[0] = dx * inv; e[1] = dy * inv; e[2] = dz * inv;
  e[3] = log1pf(norm);
  e[4] = 1.f / (1.f + expf(-(norm - 2.f)));
  e[5] = 1.f / (1.f + expf(-(norm - 4.f)));
  e[6] = 1.f / (1.f + expf(-(norm - 6.f)));
  for (int l = 0; l < 4; ++l)
    for (int h = 0; h < 8; ++h) {
      float s = 0.f;
      for (int k = 0; k < 7; ++k) s += e[k] * W_edge[(l * 7 + k) * 8 + h];
      ewb[((l * 8 + h) * 128 + i) * 128 + j] = f2bf(s);
    }
}

__global__ void k_wt(const float* __restrict__ Wv, const float* __restrict__ Wo,
                     unsigned short* __restrict__ WvT, unsigned short* __restrict__ WoT) {
  int idx = blockIdx.x * 256 + threadIdx.x;  // 4*256*256
  int l = idx >> 16, r = idx & 65535, g = r >> 8, f = r & 255;
  int src = (l << 16) + f * 256 + g;
  WvT[idx] = f2bf(Wv[src]);
  WoT[idx] = f2bf(Wo[src]);
}

// nucbT[l][g][i] = nuc_feats[i,:] @ W_nuc[l][:,g]  (fp32, transposed)
__global__ void k_nucbT(const float* __restrict__ nuc_feats, const float* __restrict__ W_nuc,
                        float* __restrict__ nucbT) {
  int b = blockIdx.x;  // l*128 + i
  int l = b >> 7, i = b & 127;
  int g = threadIdx.x;
  __shared__ float row[256];
  row[g] = nuc_feats[i * 256 + g];
  __syncthreads();
  const float* Wn = W_nuc + l * 65536;
  float s = 0.f;
  for (int f = 0; f < 256; ++f) s += row[f] * Wn[f * 256 + g];
  nucbT[(l * 256 + g) * 128 + i] = s;
}

// ---------------- fused main kernel ----------------

__global__ __launch_bounds__(512, 2) void k_main(
    float* __restrict__ feats,               // d_out [1024][128][256] fp32
    const float* __restrict__ W_orb,         // [136][256]
    const unsigned short* __restrict__ WvT,  // [4][256][256] bf16 (g-major)
    const unsigned short* __restrict__ WoT,  // [4][256][256] bf16 (g-major)
    const unsigned short* __restrict__ ewb,  // [4][8][128][128] bf16
    const float* __restrict__ nucbT,         // [4][256][128] fp32
    const int* __restrict__ orb_nuc, const int* __restrict__ orb_t) {
  __shared__ char SBUF[131072];     // s1: h/msg [128][512B]; s2: valsT [256][256B] / t
  __shared__ float lnA[2][128][2];  // LN1 cross-wave partials [g-half][row][s,ss]
  __shared__ float ln2[8][128][2];  // LN2 per-head partials   [head][row][s,ss]
  __shared__ float red[8];

  char* s1 = SBUF;
  char* s2 = SBUF + 65536;

  const int o = blockIdx.x;
  const int tid = threadIdx.x;
  const int wave = tid >> 6;
  const int lane = tid & 63;
  const int l16 = lane & 15;
  const int kgrp = (lane >> 4) << 3;  // A/B fragment k-offset: 0,8,16,24
  const int rgrp = (lane >> 4) << 2;  // D fragment row group: 0,4,8,12
  const int mh = wave & 3, gh = wave >> 2;
  const int m0 = mh * 32;    // this wave's 32 output rows
  const int G0 = gh * 128;   // this wave's g-half

  const int nn = orb_nuc[o];
  const int tt = orb_t[o];
  float* fo = feats + (size_t)o * 32768;

  // feats as MFMA accumulators: fr[mt][nti][r] = feats[m0+mt*16+rgrp+r][G0+nti*16+l16]
  f32x4 fr[2][8];
#pragma unroll
  for (int mt = 0; mt < 2; ++mt)
#pragma unroll
    for (int nti = 0; nti < 8; ++nti) {
      f32x4 v = {0.f, 0.f, 0.f, 0.f};
#pragma unroll
      for (int r = 0; r < 4; ++r) {
        const int n = m0 + mt * 16 + rgrp + r;
        if (n == nn) v[r] = W_orb[tt * 256 + G0 + nti * 16 + l16];
      }
      fr[mt][nti] = v;
    }

  for (int l = 0; l < 4; ++l) {
    // ---- LN1 stage 1: per-row partial (s,ss) over this wave's g-half ----
    {
      float sp[2][4], qp[2][4];
#pragma unroll
      for (int mt = 0; mt < 2; ++mt)
#pragma unroll
        for (int r = 0; r < 4; ++r) {
          float s = 0.f, q = 0.f;
#pragma unroll
          for (int nti = 0; nti < 8; ++nti) {
            float v = fr[mt][nti][r];
            s += v; q += v * v;
          }
          sp[mt][r] = s; qp[mt][r] = q;
        }
#pragma unroll
      for (int of = 1; of < 16; of <<= 1)
#pragma unroll
        for (int mt = 0; mt < 2; ++mt)
#pragma unroll
          for (int r = 0; r < 4; ++r) {
            sp[mt][r] += __shfl_xor(sp[mt][r], of);
            qp[mt][r] += __shfl_xor(qp[mt][r], of);
          }
      if (l16 == 0) {
#pragma unroll
        for (int mt = 0; mt < 2; ++mt)
#pragma unroll
          for (int r = 0; r < 4; ++r) {
            const int n = m0 + mt * 16 + rgrp + r;
            lnA[gh][n][0] = sp[mt][r];
            lnA[gh][n][1] = qp[mt][r];
          }
      }
    }
    __syncthreads();  // B1: lnA ready; also orders prior S1 reads vs h writes

    // ---- LN1 stage 2: center (register source), write h bf16 to S1 ----
    {
      float maxvar = 0.f;
#pragma unroll
      for (int mt = 0; mt < 2; ++mt)
#pragma unroll
        for (int r = 0; r < 4; ++r) {
          const int n = m0 + mt * 16 + rgrp + r;
          const float S = lnA[0][n][0] + lnA[1][n][0];
          const float Q = lnA[0][n][1] + lnA[1][n][1];
          const float mean = S * (1.f / 256.f);
          const float var = Q * (1.f / 256.f) - mean * mean;
          maxvar = fmaxf(maxvar, var);
#pragma unroll
          for (int nti = 0; nti < 8; ++nti)
            *(unsigned short*)(s1 + swzA(n, (G0 + nti * 16 + l16) * 2)) =
                f2bf(fr[mt][nti][r] - mean);
        }
      maxvar = fmaxf(maxvar, __shfl_xor(maxvar, 16));
      maxvar = fmaxf(maxvar, __shfl_xor(maxvar, 32));
      if (lane == 0) red[wave] = maxvar;
    }
    __syncthreads();  // B2: S1(h) + red ready

    // ---- GEMM1: valsT[g][n] = rstd * (h @ W_val), S1 -> S2 ----
    {
      float mv = red[0];
#pragma unroll
      for (int w = 1; w < 8; ++w) mv = fmaxf(mv, red[w]);
      const float rstd = rsqrtf(mv + 1.f);
      const unsigned short* Wl = WvT + l * 65536;
#pragma unroll
      for (int nti = 0; nti < 8; ++nti) {
        const int gg = G0 + nti * 16 + l16;
        const unsigned short* brow = Wl + gg * 256 + kgrp;
        bf16x8 b[8];
#pragma unroll
        for (int k0 = 0; k0 < 8; ++k0) b[k0] = *(const bf16x8*)(brow + k0 * 32);
        f32x4 acc0 = {0.f, 0.f, 0.f, 0.f}, acc1 = {0.f, 0.f, 0.f, 0.f};
#pragma unroll
        for (int k0 = 0; k0 < 8; ++k0) {
          bf16x8 a0 = *(const bf16x8*)(s1 + swzA(m0 + l16, (k0 * 32 + kgrp) * 2));
          bf16x8 a1 = *(const bf16x8*)(s1 + swzA(m0 + 16 + l16, (k0 * 32 + kgrp) * 2));
          acc0 = __builtin_amdgcn_mfma_f32_16x16x32_bf16(a0, b[k0], acc0, 0, 0, 0);
          acc1 = __builtin_amdgcn_mfma_f32_16x16x32_bf16(a1, b[k0], acc1, 0, 0, 0);
        }
        US4 o0{f2bf(acc0[0] * rstd), f2bf(acc0[1] * rstd), f2bf(acc0[2] * rstd), f2bf(acc0[3] * rstd)};
        US4 o1{f2bf(acc1[0] * rstd), f2bf(acc1[1] * rstd), f2bf(acc1[2] * rstd), f2bf(acc1[3] * rstd)};
        *(US4*)(s2 + swzV(gg, (m0 + rgrp) * 2)) = o0;
        *(US4*)(s2 + swzV(gg, (m0 + 16 + rgrp) * 2)) = o1;
      }
    }
    __syncthreads();  // B3: S2(valsT) ready

    // ---- MSG: msg[i][f] = sum_j ew[h][i][j]*valsT[f][j] + nucbT[f][i] ----
    //      + in-epilogue LN2 partial stats (per-head) -> ln2
    {
      const unsigned short* ewh = ewb + (l * 8 + wave) * 16384;
      const float* nbT = nucbT + l * 32768;
      const int f0 = wave * 32 + l16;
      const int f1 = f0 + 16;
      bf16x8 B0[4], B1[4];  // hoisted: this head's valsT rows, full K=128
#pragma unroll
      for (int k0 = 0; k0 < 4; ++k0) {
        B0[k0] = *(const bf16x8*)(s2 + swzV(wave * 32 + l16, (k0 * 32 + kgrp) * 2));
        B1[k0] = *(const bf16x8*)(s2 + swzV(wave * 32 + 16 + l16, (k0 * 32 + kgrp) * 2));
      }
#pragma unroll
      for (int mt = 0; mt < 8; ++mt) {
        const int i0 = mt * 16;
        bf16x8 a[4];
#pragma unroll
        for (int k0 = 0; k0 < 4; ++k0)
          a[k0] = *(const bf16x8*)(ewh + (i0 + l16) * 128 + k0 * 32 + kgrp);
        f32x4 acc0 = {0.f, 0.f, 0.f, 0.f}, acc1 = {0.f, 0.f, 0.f, 0.f};
#pragma unroll
        for (int k0 = 0; k0 < 4; ++k0) {
          acc0 = __builtin_amdgcn_mfma_f32_16x16x32_bf16(a[k0], B0[k0], acc0, 0, 0, 0);
          acc1 = __builtin_amdgcn_mfma_f32_16x16x32_bf16(a[k0], B1[k0], acc1, 0, 0, 0);
        }
        const f32x4 nb0 = *(const f32x4*)(nbT + f0 * 128 + i0 + rgrp);
        const f32x4 nb1 = *(const f32x4*)(nbT + f1 * 128 + i0 + rgrp);
        float sp[4], qp[4];
#pragma unroll
        for (int r = 0; r < 4; ++r) {
          const float v0 = acc0[r] + nb0[r];
          const float v1 = acc1[r] + nb1[r];
          *(unsigned short*)(s1 + swzA(i0 + rgrp + r, f0 * 2)) = f2bf(v0);
          *(unsigned short*)(s1 + swzA(i0 + rgrp + r, f1 * 2)) = f2bf(v1);
          sp[r] = v0 + v1;
          qp[r] = v0 * v0 + v1 * v1;
        }
#pragma unroll
        for (int of = 1; of < 16; of <<= 1)
#pragma unroll
          for (int r = 0; r < 4; ++r) {
            sp[r] += __shfl_xor(sp[r], of);
            qp[r] += __shfl_xor(qp[r], of);
          }
        if (l16 == 0) {
#pragma unroll
          for (int r = 0; r < 4; ++r) {
            ln2[wave][i0 + rgrp + r][0] = sp[r];
            ln2[wave][i0 + rgrp + r][1] = qp[r];
          }
        }
      }
    }
    __syncthreads();  // B4: S1(msg) + ln2 ready

    // ---- LN2 combine (redundant per wave, no extra barrier) + pass B ----
    {
      float s0 = 0.f, q0 = 0.f, s1v = 0.f, q1v = 0.f;
#pragma unroll
      for (int h = 0; h < 8; ++h) {
        s0 += ln2[h][lane][0];        q0 += ln2[h][lane][1];
        s1v += ln2[h][lane + 64][0];  q1v += ln2[h][lane + 64][1];
      }
      const float mean_a = s0 * (1.f / 256.f);
      const float mean_b = s1v * (1.f / 256.f);
      float v0 = q0 * (1.f / 256.f) - mean_a * mean_a;
      float v1 = q1v * (1.f / 256.f) - mean_b * mean_b;
      float mv = fmaxf(v0, v1);
#pragma unroll
      for (int of = 1; of < 64; of <<= 1) mv = fmaxf(mv, __shfl_xor(mv, of));
      const float rstd2 = rsqrtf(mv + 1.f);
      const float meansel = (wave >= 4) ? mean_b : mean_a;
      // t = tanh((msg - mean) * rstd2): wave handles rows wave*16..+16
#pragma unroll
      for (int r = 0; r < 16; ++r) {
        const int n = wave * 16 + r;
        const float mn = __shfl(meansel, ((wave & 3) << 4) + r);
        US4 x4 = *(const US4*)(s1 + swzA(n, lane * 8));
        US4 t4{f2bf(ftanh((bf2f(x4.a) - mn) * rstd2)),
               f2bf(ftanh((bf2f(x4.b) - mn) * rstd2)),
               f2bf(ftanh((bf2f(x4.c) - mn) * rstd2)),
               f2bf(ftanh((bf2f(x4.d) - mn) * rstd2))};
        *(US4*)(s2 + swzA(n, lane * 8)) = t4;
      }
    }
    __syncthreads();  // B5: S2(t) ready

    // ---- GEMM2: fr = t @ W_out + fr (fr seeds the MFMA accumulator chain) ----
    {
      const unsigned short* Wl = WoT + l * 65536;
#pragma unroll
      for (int nti = 0; nti < 8; ++nti) {
        const unsigned short* brow = Wl + (G0 + nti * 16 + l16) * 256 + kgrp;
        bf16x8 b[8];
#pragma unroll
        for (int k0 = 0; k0 < 8; ++k0) b[k0] = *(const bf16x8*)(brow + k0 * 32);
        f32x4 acc0 = fr[0][nti];
        f32x4 acc1 = fr[1][nti];
#pragma unroll
        for (int k0 = 0; k0 < 8; ++k0) {
          bf16x8 a0 = *(const bf16x8*)(s2 + swzA(m0 + l16, (k0 * 32 + kgrp) * 2));
          bf16x8 a1 = *(const bf16x8*)(s2 + swzA(m0 + 16 + l16, (k0 * 32 + kgrp) * 2));
          acc0 = __builtin_amdgcn_mfma_f32_16x16x32_bf16(a0, b[k0], acc0, 0, 0, 0);
          acc1 = __builtin_amdgcn_mfma_f32_16x16x32_bf16(a1, b[k0], acc1, 0, 0, 0);
        }
        fr[0][nti] = acc0;
        fr[1][nti] = acc1;
      }
    }
    // no barrier needed: next phase touching LDS is LN1 stage2 (after next B1)
  }

  // ---- final store: stage fp32 through LDS for coalesced float4 stores ----
  __syncthreads();
  float* stage = (float*)SBUF;
#pragma unroll
  for (int mt = 0; mt < 2; ++mt)
#pragma unroll
    for (int nti = 0; nti < 8; ++nti)
#pragma unroll
      for (int r = 0; r < 4; ++r) {
        const int n = m0 + mt * 16 + rgrp + r;
        stage[n * 256 + G0 + nti * 16 + l16] = fr[mt][nti][r];
      }
  __syncthreads();
#pragma unroll
  for (int it = 0; it < 16; ++it) {
    const int idx = (it * 512 + tid) * 4;
    *(f32x4*)(fo + idx) = *(const f32x4*)(stage + idx);
  }
}

// ---------------- launcher ----------------

extern "C" void kernel_launch(void* const* d_in, const int* in_sizes, int n_in,
                              void* d_out, int out_size, void* d_ws, size_t ws_size,
                              hipStream_t stream) {
  const float* coords = (const float*)d_in[0];
  const int* charges = (const int*)d_in[1];
  const int* n_up = (const int*)d_in[3];
  const int* n_down = (const int*)d_in[4];
  const float* nuc_feats = (const float*)d_in[5];
  const float* W_orb = (const float*)d_in[7];
  const float* W_edge = (const float*)d_in[8];
  const float* W_val = (const float*)d_in[9];
  const float* W_nuc = (const float*)d_in[10];
  const float* W_out = (const float*)d_in[11];
  float* out = (float*)d_out;

  char* ws = (char*)d_ws;
  int* orb_nuc = (int*)ws;                                        // 4KB
  int* orb_t = (int*)(ws + 4096);                                 // 4KB
  unsigned short* ewb = (unsigned short*)(ws + 8192);             // 1MB
  unsigned short* WvT = (unsigned short*)(ws + 8192 + 1048576);   // 512KB
  unsigned short* WoT = WvT + 262144;                             // 512KB
  float* nucbT = (float*)(ws + 8192 + 1048576 + 1048576);         // 512KB

  k_orbmap<<<dim3(1), dim3(256), 0, stream>>>(charges, n_up, n_down, orb_nuc, orb_t);
  k_ew<<<dim3(128), dim3(128), 0, stream>>>(coords, W_edge, ewb);
  k_wt<<<dim3(1024), dim3(256), 0, stream>>>(W_val, W_out, WvT, WoT);
  k_nucbT<<<dim3(512), dim3(256), 0, stream>>>(nuc_feats, W_nuc, nucbT);
  k_main<<<dim3(O_TOT), dim3(512), 0, stream>>>(out, W_orb, WvT, WoT, ewb, nucbT,
                                                orb_nuc, orb_t);
}